// Round 1
// baseline (70.769 us; speedup 1.0000x reference)
//
#include <hip/hip_runtime.h>

// YOLOv1 loss: N=4096, S=14, B=2, D=30. Memory-bound map-reduce.
// One thread per (n,i,j) cell; reads 30 floats pred + 30 floats targ as float2
// (cell stride 120 B is 8B-aligned). Per-thread partials -> wave shfl reduce ->
// LDS across waves -> atomicAdd to d_ws[5] -> tiny finalize kernel.

constexpr int SS = 14;

__global__ __launch_bounds__(256) void yolo_cells(
    const float* __restrict__ pred,
    const float* __restrict__ targ,
    float* __restrict__ sums,   // d_ws: 5 floats (raw sums)
    int ncells)
{
    int cell = blockIdx.x * 256 + threadIdx.x;
    float s0 = 0.f, s1 = 0.f, s2 = 0.f, s3 = 0.f, s4 = 0.f; // xy, wh, Cobj, Cnoobj, class

    if (cell < ncells) {
        const float2* p2 = reinterpret_cast<const float2*>(pred) + (size_t)cell * 15;
        const float2* t2 = reinterpret_cast<const float2*>(targ) + (size_t)cell * 15;
        float p[30], t[30];
#pragma unroll
        for (int i = 0; i < 15; ++i) { float2 v = p2[i]; p[2*i] = v.x; p[2*i+1] = v.y; }
#pragma unroll
        for (int i = 0; i < 15; ++i) { float2 v = t2[i]; t[2*i] = v.x; t[2*i+1] = v.y; }

        int ij = cell % (SS * SS);
        float offx = (float)(ij % SS);  // off = (j, i): x = column
        float offy = (float)(ij / SS);

        float obj = t[4];
        float m  = (obj == 1.0f) ? 1.0f : 0.0f;
        float nm = (obj == 0.0f) ? 1.0f : 0.0f;

        const float S = 14.0f;
        // target box -> xyxy
        float tcx = t[0] / S + offx / S;
        float tcy = t[1] / S + offy / S;
        float thw = 0.5f * t[2], thh = 0.5f * t[3];
        float tx0 = tcx - thw, ty0 = tcy - thh;
        float tx1 = tcx + thw, ty1 = tcy + thh;
        float area_t = t[2] * t[3];

        float iou0, iou1;
        {
            float cx = p[0] / S + offx / S, cy = p[1] / S + offy / S;
            float hw = 0.5f * p[2], hh = 0.5f * p[3];
            float x0 = cx - hw, y0 = cy - hh, x1 = cx + hw, y1 = cy + hh;
            float wx = fmaxf(fminf(tx1, x1) - fmaxf(tx0, x0), 0.f);
            float wy = fmaxf(fminf(ty1, y1) - fmaxf(ty0, y0), 0.f);
            float inter = wx * wy;
            iou0 = inter / (area_t + p[2] * p[3] - inter);
        }
        {
            float cx = p[5] / S + offx / S, cy = p[6] / S + offy / S;
            float hw = 0.5f * p[7], hh = 0.5f * p[8];
            float x0 = cx - hw, y0 = cy - hh, x1 = cx + hw, y1 = cy + hh;
            float wx = fmaxf(fminf(tx1, x1) - fmaxf(tx0, x0), 0.f);
            float wy = fmaxf(fminf(ty1, y1) - fmaxf(ty0, y0), 0.f);
            float inter = wx * wy;
            iou1 = inter / (area_t + p[7] * p[8] - inter);
        }

        // jnp.argmax picks first max on ties -> k=1 only if strictly greater
        int k = (iou1 > iou0) ? 1 : 0;
        const float* bp = p + 5 * k;
        float biou = k ? iou1 : iou0;

        float d0 = t[0] - bp[0], d1 = t[1] - bp[1];
        s0 = m * (d0 * d0 + d1 * d1);

        float e0 = sqrtf(t[2]) - sqrtf(bp[2]);
        float e1 = sqrtf(t[3]) - sqrtf(bp[3]);
        s1 = m * (e0 * e0 + e1 * e1);

        float dc = biou - bp[4];
        s2 = m * dc * dc;

        float conf_other = k ? p[4] : p[9];  // conf of the non-best box
        s3 = nm * (p[4] * p[4] + p[9] * p[9]) + m * conf_other * conf_other;

        float cls = 0.f;
#pragma unroll
        for (int c = 10; c < 30; ++c) { float d = t[c] - p[c]; cls += d * d; }
        s4 = m * cls;
    }

    // wave (64-lane) butterfly reduce
#pragma unroll
    for (int o = 32; o > 0; o >>= 1) {
        s0 += __shfl_down(s0, o);
        s1 += __shfl_down(s1, o);
        s2 += __shfl_down(s2, o);
        s3 += __shfl_down(s3, o);
        s4 += __shfl_down(s4, o);
    }

    __shared__ float red[4][5];
    int wave = threadIdx.x >> 6;
    int lane = threadIdx.x & 63;
    if (lane == 0) {
        red[wave][0] = s0; red[wave][1] = s1; red[wave][2] = s2;
        red[wave][3] = s3; red[wave][4] = s4;
    }
    __syncthreads();
    if (threadIdx.x < 5) {
        float r = red[0][threadIdx.x] + red[1][threadIdx.x] +
                  red[2][threadIdx.x] + red[3][threadIdx.x];
        atomicAdd(&sums[threadIdx.x], r);
    }
}

__global__ void yolo_final(const float* __restrict__ sums,
                           float* __restrict__ out, float invN)
{
    float xy     = sums[0] * 5.0f * invN;
    float wh     = sums[1] * 5.0f * invN;
    float cobj   = sums[2] * invN;
    float cnoobj = sums[3] * 0.5f * invN;
    float cls    = sums[4] * invN;
    out[0] = xy + wh + cobj + cnoobj + cls;
    out[1] = xy;
    out[2] = wh;
    out[3] = cobj;
    out[4] = cnoobj;
    out[5] = cls;
}

extern "C" void kernel_launch(void* const* d_in, const int* in_sizes, int n_in,
                              void* d_out, int out_size, void* d_ws, size_t ws_size,
                              hipStream_t stream)
{
    const float* pred = (const float*)d_in[0];
    const float* targ = (const float*)d_in[1];
    int ncells = in_sizes[0] / 30;          // N * S * S
    int N = ncells / (SS * SS);
    float* sums = (float*)d_ws;

    hipMemsetAsync(sums, 0, 5 * sizeof(float), stream);

    int grid = (ncells + 255) / 256;
    yolo_cells<<<grid, 256, 0, stream>>>(pred, targ, sums, ncells);
    yolo_final<<<1, 1, 0, stream>>>(sums, (float*)d_out, 1.0f / (float)N);
}